// Round 1
// baseline (319.695 us; speedup 1.0000x reference)
//
#include <hip/hip_runtime.h>
#include <math.h>

#define PATCH 41
#define PSIZE (PATCH * PATCH)   // 1681
#define NUM_ANG 8
#define KS 16                   // BIN_KSIZE
#define STRIDE 10               // BIN_STRIDE
#define PAD 4                   // BIN_PAD
#define DESC 128
#define CLIPVAL 0.2f

// Block-wide sum over 256 threads (threads with no value pass 0).
__device__ __forceinline__ float block_sum256(float v, float* red, int tid) {
    #pragma unroll
    for (int off = 32; off >= 1; off >>= 1) v += __shfl_xor(v, off);
    __syncthreads();                 // protect red[] from previous use
    if ((tid & 63) == 0) red[tid >> 6] = v;
    __syncthreads();
    return red[0] + red[1] + red[2] + red[3];
}

__global__ __launch_bounds__(256) void sift_desc_kernel(
    const float* __restrict__ input,
    const float* __restrict__ gk,
    const float* __restrict__ pk,
    float* __restrict__ out)
{
    __shared__ float s_patch[PSIZE];
    __shared__ float s_gk[PSIZE];
    __shared__ float s_pk[KS * KS];
    __shared__ float s_hist[DESC];
    __shared__ float s_red[4];

    const int tid = threadIdx.x;
    const int b   = blockIdx.x;
    const float* in_p = input + (size_t)b * PSIZE;

    for (int p = tid; p < PSIZE; p += 256) {
        s_patch[p] = in_p[p];
        s_gk[p]    = gk[p];
    }
    if (tid < KS * KS) s_pk[tid] = pk[tid];
    if (tid < DESC)    s_hist[tid] = 0.0f;
    __syncthreads();

    const float kPi     = 3.14159265358979323846f;
    const float o_scale = (float)NUM_ANG / (2.0f * kPi);

    for (int p = tid; p < PSIZE; p += 256) {
        const int y = p / PATCH;
        const int x = p - y * PATCH;
        const int xm = (x > 0)         ? x - 1 : 0;
        const int xp = (x < PATCH - 1) ? x + 1 : PATCH - 1;
        const int ym = (y > 0)         ? y - 1 : 0;
        const int yp = (y < PATCH - 1) ? y + 1 : PATCH - 1;

        // spatial_gradient(mode='diff', normalized): 0.5 * central diff, replicate pad
        const float gx = 0.5f * (s_patch[y * PATCH + xp] - s_patch[y * PATCH + xm]);
        const float gy = 0.5f * (s_patch[yp * PATCH + x] - s_patch[ym * PATCH + x]);

        const float mag = sqrtf(gx * gx + gy * gy + 1e-10f) * s_gk[p];
        const float ori = atan2f(gy, gx + 1e-10f) + 2.0f * kPi;   // in (pi, 3pi]

        const float o_big = ori * o_scale;           // in (4, 12]
        const float bo0f  = floorf(o_big);
        const float wo1f  = o_big - bo0f;
        const int bo0 = ((int)bo0f) & (NUM_ANG - 1);
        const int bo1 = (bo0 + 1) & (NUM_ANG - 1);
        const float wo0 = (1.0f - wo1f) * mag;
        const float wo1 = wo1f * mag;

        // pooling windows covering (y,x): window i spans rows [i*10-4, i*10+11]
        const int i_lo = (y >= 12) ? (y - 2) / 10 : 0;
        const int i_hi = min(3, (y + 4) / 10);
        const int j_lo = (x >= 12) ? (x - 2) / 10 : 0;
        const int j_hi = min(3, (x + 4) / 10);

        for (int i = i_lo; i <= i_hi; ++i) {
            const int dy = y - i * STRIDE + PAD;       // 0..15
            for (int j = j_lo; j <= j_hi; ++j) {
                const int dx = x - j * STRIDE + PAD;   // 0..15
                const float w = s_pk[dy * KS + dx];
                const int cell = i * 4 + j;
                atomicAdd(&s_hist[bo0 * 16 + cell], wo0 * w);
                atomicAdd(&s_hist[bo1 * 16 + cell], wo1 * w);
            }
        }
    }
    __syncthreads();

    // --- normalization chain: l2n -> clip(0,0.2) -> l2n -> rootsift ---
    const float v = (tid < DESC) ? s_hist[tid] : 0.0f;

    const float ss1 = block_sum256(v * v, s_red, tid);
    float a = v / fmaxf(sqrtf(ss1), 1e-12f);
    a = fminf(fmaxf(a, 0.0f), CLIPVAL);

    const float ss2 = block_sum256(a * a, s_red, tid);
    const float bn = a / fmaxf(sqrtf(ss2), 1e-12f);

    const float l1 = block_sum256(fabsf(bn), s_red, tid);
    const float o  = sqrtf(bn / fmaxf(l1, 1e-12f) + 1e-10f);

    if (tid < DESC) out[(size_t)b * DESC + tid] = o;
}

extern "C" void kernel_launch(void* const* d_in, const int* in_sizes, int n_in,
                              void* d_out, int out_size, void* d_ws, size_t ws_size,
                              hipStream_t stream) {
    const float* input = (const float*)d_in[0];
    const float* gk    = (const float*)d_in[1];
    const float* pk    = (const float*)d_in[2];
    float* out         = (float*)d_out;

    const int B = in_sizes[0] / PSIZE;
    if (B <= 0) return;
    sift_desc_kernel<<<dim3(B), dim3(256), 0, stream>>>(input, gk, pk, out);
}

// Round 3
// 81.539 us; speedup vs baseline: 3.9207x; 3.9207x over previous
//
#include <hip/hip_runtime.h>
#include <math.h>

#define PATCH 41
#define PSIZE (PATCH * PATCH)   // 1681
#define NUM_ANG 8
#define KS 16                   // BIN_KSIZE
#define STRIDE 10               // BIN_STRIDE
#define PAD 4                   // BIN_PAD
#define DESC 128
#define CLIPVAL 0.2f

// Block-wide sum over 256 threads (threads with no value pass 0).
__device__ __forceinline__ float block_sum256(float v, float* red, int tid) {
    #pragma unroll
    for (int off = 32; off >= 1; off >>= 1) v += __shfl_xor(v, off);
    __syncthreads();                 // protect red[] from previous use
    if ((tid & 63) == 0) red[tid >> 6] = v;
    __syncthreads();
    return red[0] + red[1] + red[2] + red[3];
}

__global__ __launch_bounds__(256) void sift_desc_kernel(
    const float* __restrict__ input,
    const float* __restrict__ gk,
    const float* __restrict__ pk,
    float* __restrict__ out)
{
    __shared__ float2 s_om[PSIZE];     // per-pixel (o_big, gk-weighted mag)
    __shared__ float  s_patch[PSIZE];  // raw patch; reused as colsum[41][4][8] after phase 1
    __shared__ float  s_red[4];

    const int tid = threadIdx.x;
    const int b   = blockIdx.x;
    const float* in_p = input + (size_t)b * PSIZE;

    // Separable pooling weights: pk = outer(w, w) with w >= 0, so w[d] = sqrt(pk[d][d]).
    float w1r[KS];
    #pragma unroll
    for (int d = 0; d < KS; ++d) w1r[d] = sqrtf(pk[d * KS + d]);

    for (int p = tid; p < PSIZE; p += 256) s_patch[p] = in_p[p];
    __syncthreads();

    // ---- phase 1: per-pixel orientation (in bin units) + weighted magnitude ----
    for (int p = tid; p < PSIZE; p += 256) {
        const int y = p / PATCH;
        const int x = p - y * PATCH;
        const int xm = max(x - 1, 0), xp = min(x + 1, PATCH - 1);
        const int ym = max(y - 1, 0), yp = min(y + 1, PATCH - 1);

        const float gx = 0.5f * (s_patch[y * PATCH + xp] - s_patch[y * PATCH + xm]);
        const float gy = 0.5f * (s_patch[yp * PATCH + x] - s_patch[ym * PATCH + x]);

        const float mag  = sqrtf(gx * gx + gy * gy + 1e-10f) * gk[p];
        // o_big = 8*(atan2+2pi)/(2pi) = atan2*(4/pi) + 8
        const float obig = atan2f(gy, gx + 1e-10f) * 1.27323954473516f + 8.0f;
        s_om[p] = make_float2(obig, mag);
    }
    __syncthreads();

    // ---- phase 2a: separable pooling along x, one thread per (angle, j, y-slice) ----
    // contribution of pixel to angle a: mag * max(0, 1 - |wrap8(o_big - a)|)
    float* colsum = s_patch;   // [41][4][8] = 1312 floats, fits in dead patch buffer
    {
        const int a  = tid & 7;
        const int j  = (tid >> 3) & 3;
        const int y0 = tid >> 5;            // 0..7
        const float af  = (float)a;
        const int   px0 = j * STRIDE - PAD;
        for (int y = y0; y < PATCH; y += 8) {
            const float2* rowp = s_om + y * PATCH;
            float acc = 0.0f;
            #pragma unroll
            for (int dx = 0; dx < KS; ++dx) {
                const int px  = px0 + dx;
                const int pxc = min(max(px, 0), PATCH - 1);
                const float2 om = rowp[pxc];            // broadcast across 8 angle-lanes
                float u = om.x - af;
                u -= 8.0f * rintf(u * 0.125f);          // wrap to [-4, 4]
                const float t  = fmaxf(0.0f, 1.0f - fabsf(u));
                const float wv = (px == pxc) ? w1r[dx] : 0.0f;  // zero weight when clipped
                acc = fmaf(t * wv, om.y, acc);
            }
            colsum[y * 32 + j * 8 + a] = acc;
        }
    }
    __syncthreads();

    // ---- phase 2b: pooling along y -> one descriptor value per tid < 128 ----
    float v = 0.0f;
    int a = 0, jj = 0, ii = 0;
    if (tid < DESC) {
        a = tid & 7; jj = (tid >> 3) & 3; ii = tid >> 5;
        const int py0 = ii * STRIDE - PAD;
        #pragma unroll
        for (int dy = 0; dy < KS; ++dy) {
            const int py = py0 + dy;
            if (py >= 0 && py < PATCH)
                v = fmaf(w1r[dy], colsum[py * 32 + jj * 8 + a], v);
        }
    }

    // ---- normalization chain: l2n -> clip -> l2n -> rootsift ----
    // (all sums are permutation-invariant, so thread->descriptor-slot order
    //  only matters at the final store)
    const float ss1 = block_sum256(v * v, s_red, tid);
    float aa = v / fmaxf(sqrtf(ss1), 1e-12f);
    aa = fminf(fmaxf(aa, 0.0f), CLIPVAL);

    const float ss2 = block_sum256(aa * aa, s_red, tid);
    const float bn = aa / fmaxf(sqrtf(ss2), 1e-12f);

    const float l1 = block_sum256(fabsf(bn), s_red, tid);
    const float o  = sqrtf(bn / fmaxf(l1, 1e-12f) + 1e-10f);

    // reference layout: desc[ang*16 + i*4 + j]
    if (tid < DESC) out[(size_t)b * DESC + (a * 16 + ii * 4 + jj)] = o;
}

extern "C" void kernel_launch(void* const* d_in, const int* in_sizes, int n_in,
                              void* d_out, int out_size, void* d_ws, size_t ws_size,
                              hipStream_t stream) {
    const float* input = (const float*)d_in[0];
    const float* gk    = (const float*)d_in[1];
    const float* pk    = (const float*)d_in[2];
    float* out         = (float*)d_out;

    const int B = in_sizes[0] / PSIZE;
    if (B <= 0) return;
    sift_desc_kernel<<<dim3(B), dim3(256), 0, stream>>>(input, gk, pk, out);
}

// Round 4
// 75.688 us; speedup vs baseline: 4.2239x; 1.0773x over previous
//
#include <hip/hip_runtime.h>
#include <hip/hip_fp16.h>
#include <math.h>

#define PATCH 41
#define PSIZE (PATCH * PATCH)   // 1681
#define NUM_ANG 8
#define KS 16                   // BIN_KSIZE
#define STRIDE 10               // BIN_STRIDE
#define PAD 4                   // BIN_PAD
#define DESC 128
#define CLIPVAL 0.2f

// Block-wide sum over 256 threads (threads with no value pass 0).
__device__ __forceinline__ float block_sum256(float v, float* red, int tid) {
    #pragma unroll
    for (int off = 32; off >= 1; off >>= 1) v += __shfl_xor(v, off);
    __syncthreads();                 // protect red[] from previous use
    if ((tid & 63) == 0) red[tid >> 6] = v;
    __syncthreads();
    return red[0] + red[1] + red[2] + red[3];
}

__global__ __launch_bounds__(256) void sift_desc_kernel(
    const float* __restrict__ input,
    const float* __restrict__ gk,
    const float* __restrict__ pk,
    float* __restrict__ out)
{
    // angle-interleaved per-pixel bin weights: arr[p][a], f16, x1024 scale
    __shared__ __half s_arr[PSIZE * NUM_ANG];          // 26896 B
    __shared__ float  s_patch[PSIZE];                  // 6724 B
    __shared__ float  s_colsum[PATCH * 32];            // [41][4j][8a] = 5248 B
    __shared__ float  s_red[4];

    const int tid = threadIdx.x;
    const int b   = blockIdx.x;
    const float* in_p = input + (size_t)b * PSIZE;

    // Separable pooling weights: pk = outer(w, w), w >= 0 -> w[d] = sqrt(pk[d][d]).
    float w1r[KS];
    #pragma unroll
    for (int d = 0; d < KS; ++d) w1r[d] = sqrtf(pk[d * KS + d]);

    // ---- phase 0: stage patch, zero the angle array ----
    for (int p = tid; p < PSIZE; p += 256) s_patch[p] = in_p[p];
    {
        float4* z = (float4*)s_arr;                    // 1681 x 16B
        const float4 zero = make_float4(0.f, 0.f, 0.f, 0.f);
        for (int i = tid; i < PSIZE; i += 256) z[i] = zero;
    }
    __syncthreads();

    // ---- phase 1: per-pixel gradient -> orientation bins (octant units) ----
    // obig in [0,8) equals 8*(atan2(gy,gx+eps)+2pi)/(2pi) mod 8.
    for (int p = tid; p < PSIZE; p += 256) {
        const int y = p / PATCH;
        const int x = p - y * PATCH;
        const int xm = max(x - 1, 0), xp = min(x + 1, PATCH - 1);
        const int ym = max(y - 1, 0), yp = min(y + 1, PATCH - 1);

        const float gx = 0.5f * (s_patch[y * PATCH + xp] - s_patch[y * PATCH + xm]);
        const float gy = 0.5f * (s_patch[yp * PATCH + x] - s_patch[ym * PATCH + x]);

        const float mag = sqrtf(gx * gx + gy * gy + 1e-10f) * gk[p] * 1024.0f;

        // custom atan2 in octant units (x 4/pi), |err| <= ~1.3e-5
        const float gxp = gx + 1e-10f;
        const float ax = fabsf(gxp), ay = fabsf(gy);
        const float mx = fmaxf(fmaxf(ax, ay), 1e-20f);
        const float t  = fminf(ax, ay) / mx;
        const float s  = t * t;
        float r = t * (1.27306897f + s * (-0.42055650f + s * (0.22936229f
                      + s * (-0.10839420f + s * 0.02652810f))));
        if (ay > ax)     r = 2.0f - r;
        if (gxp < 0.0f)  r = 4.0f - r;
        if (gy < 0.0f)   r = 8.0f - r;     // obig in [0, 8]

        const float bo0f = floorf(r);
        const float f    = r - bo0f;
        const int bo0 = ((int)bo0f) & (NUM_ANG - 1);
        const int bo1 = (bo0 + 1) & (NUM_ANG - 1);

        __half* slot = s_arr + p * NUM_ANG;
        slot[bo0] = __float2half((1.0f - f) * mag);
        slot[bo1] = __float2half(f * mag);
    }
    __syncthreads();

    // ---- phase 2a: x-pooling; each thread: one angle-PAIR x j-window x y-slice ----
    {
        const int a0 = (tid & 3) * 2;          // angles a0, a0+1
        const int j  = (tid >> 2) & 3;
        const int y0 = tid >> 4;               // 0..15
        const int px0 = j * STRIDE - PAD;
        for (int y = y0; y < PATCH; y += 16) {
            float acc0 = 0.0f, acc1 = 0.0f;
            const int rowbase = y * PATCH;
            #pragma unroll
            for (int dx = 0; dx < KS; ++dx) {
                const int px  = px0 + dx;
                const int pxc = min(max(px, 0), PATCH - 1);
                const float wv = (px == pxc) ? w1r[dx] : 0.0f;
                const __half2 h = *(const __half2*)(s_arr + (rowbase + pxc) * NUM_ANG + a0);
                acc0 = fmaf(wv, __half2float(h.x), acc0);
                acc1 = fmaf(wv, __half2float(h.y), acc1);
            }
            *(float2*)(s_colsum + y * 32 + j * 8 + a0) = make_float2(acc0, acc1);
        }
    }
    __syncthreads();

    // ---- phase 2b: y-pooling -> one descriptor value per tid < 128 ----
    float v = 0.0f;
    int a = 0, jj = 0, ii = 0;
    if (tid < DESC) {
        a = tid & 7; jj = (tid >> 3) & 3; ii = tid >> 5;
        const int py0 = ii * STRIDE - PAD;
        #pragma unroll
        for (int dy = 0; dy < KS; ++dy) {
            const int py  = py0 + dy;
            const int pyc = min(max(py, 0), PATCH - 1);
            const float wv = (py == pyc) ? w1r[dy] : 0.0f;
            v = fmaf(wv, s_colsum[pyc * 32 + jj * 8 + a], v);
        }
    }

    // ---- normalization chain: l2n -> clip -> l2n -> rootsift ----
    // (x1024 global scale cancels in the first l2-normalize)
    const float ss1 = block_sum256(v * v, s_red, tid);
    float aa = v / fmaxf(sqrtf(ss1), 1e-12f);
    aa = fminf(fmaxf(aa, 0.0f), CLIPVAL);

    const float ss2 = block_sum256(aa * aa, s_red, tid);
    const float bn = aa / fmaxf(sqrtf(ss2), 1e-12f);

    const float l1 = block_sum256(fabsf(bn), s_red, tid);
    const float o  = sqrtf(bn / fmaxf(l1, 1e-12f) + 1e-10f);

    // reference layout: desc[ang*16 + i*4 + j]
    if (tid < DESC) out[(size_t)b * DESC + (a * 16 + ii * 4 + jj)] = o;
}

extern "C" void kernel_launch(void* const* d_in, const int* in_sizes, int n_in,
                              void* d_out, int out_size, void* d_ws, size_t ws_size,
                              hipStream_t stream) {
    const float* input = (const float*)d_in[0];
    const float* gk    = (const float*)d_in[1];
    const float* pk    = (const float*)d_in[2];
    float* out         = (float*)d_out;

    const int B = in_sizes[0] / PSIZE;
    if (B <= 0) return;
    sift_desc_kernel<<<dim3(B), dim3(256), 0, stream>>>(input, gk, pk, out);
}